// Round 1
// baseline (521.141 us; speedup 1.0000x reference)
//
#include <hip/hip_runtime.h>
#include <math.h>

#define EMB 64

__global__ __launch_bounds__(256) void consrec_kernel(
    const float* __restrict__ user_emb,
    const float* __restrict__ item_emb,
    const float* __restrict__ w1,     // [64][8]
    const float* __restrict__ b1,     // [8]
    const float* __restrict__ w2,     // [8]
    const float* __restrict__ b2,     // [1]
    const int*   __restrict__ member_users,
    const int*   __restrict__ member_groups,  // sorted ascending
    const int*   __restrict__ group_inputs,
    const int*   __restrict__ item_inputs,
    int num_members,
    int batch,
    float* __restrict__ out)
{
    const int wave = (int)((blockIdx.x * blockDim.x + threadIdx.x) >> 6);
    const int lane = threadIdx.x & 63;
    if (wave >= batch) return;

    const int g = group_inputs[wave];

    // lower_bound(g) — lane-uniform binary search (addresses identical across
    // lanes -> cache broadcast; member_groups is 12.8 MB, L3-resident)
    int lo = 0, hi = num_members;
    while (lo < hi) {
        int mid = (lo + hi) >> 1;
        if (member_groups[mid] < g) lo = mid + 1; else hi = mid;
    }
    const int start = lo;
    hi = num_members;
    while (lo < hi) {
        int mid = (lo + hi) >> 1;
        if (member_groups[mid] <= g) lo = mid + 1; else hi = mid;
    }
    const int end = lo;

    // segment mean over this group's members; lane d owns dim d.
    float sum = 0.f;
    for (int j = start; j < end; ++j) {
        const int u = member_users[j];               // lane-uniform load
        sum += user_emb[(size_t)u * EMB + lane];     // coalesced 256B/member
    }
    const int cnt = end - start;
    const float mean = sum / (float)(cnt > 0 ? cnt : 1);

    const float x = mean * item_emb[(size_t)item_inputs[wave] * EMB + lane];

    // h = relu(x @ w1 + b1): lane d contributes x[d] * w1[d][k]
    float p[8];
    #pragma unroll
    for (int k = 0; k < 8; ++k) p[k] = x * w1[lane * 8 + k];

    #pragma unroll
    for (int off = 32; off >= 1; off >>= 1) {
        #pragma unroll
        for (int k = 0; k < 8; ++k) p[k] += __shfl_xor(p[k], off, 64);
    }

    float acc = b2[0];
    #pragma unroll
    for (int k = 0; k < 8; ++k) {
        float h = p[k] + b1[k];
        h = h > 0.f ? h : 0.f;
        acc += h * w2[k];
    }
    const float y = 1.f / (1.f + expf(-acc));
    if (lane == 0) out[wave] = y;
}

extern "C" void kernel_launch(void* const* d_in, const int* in_sizes, int n_in,
                              void* d_out, int out_size, void* d_ws, size_t ws_size,
                              hipStream_t stream) {
    const float* user_emb      = (const float*)d_in[0];
    const float* item_emb      = (const float*)d_in[1];
    const float* w1            = (const float*)d_in[2];
    const float* b1            = (const float*)d_in[3];
    const float* w2            = (const float*)d_in[4];
    const float* b2            = (const float*)d_in[5];
    const int*   member_users  = (const int*)d_in[6];
    const int*   member_groups = (const int*)d_in[7];
    const int*   group_inputs  = (const int*)d_in[8];
    const int*   item_inputs   = (const int*)d_in[9];

    const int num_members = in_sizes[6];
    const int batch       = in_sizes[8];

    const int threads = 256;                 // 4 waves/block
    const int waves_per_block = threads / 64;
    const int grid = (batch + waves_per_block - 1) / waves_per_block;

    consrec_kernel<<<grid, threads, 0, stream>>>(
        user_emb, item_emb, w1, b1, w2, b2,
        member_users, member_groups, group_inputs, item_inputs,
        num_members, batch, (float*)d_out);
}

// Round 2
// 443.398 us; speedup vs baseline: 1.1753x; 1.1753x over previous
//
#include <hip/hip_runtime.h>
#include <math.h>

#define EMB 64

// Pass 1: offs[g] = lower_bound(member_groups, g) for g in [0, G]; offs[G] = M.
// member_groups is sorted ascending. Each thread j fills offs for every group
// whose range starts at j (gap-fill between mg[j-1] and mg[j]).
__global__ __launch_bounds__(256) void boundaries_kernel(
    const int* __restrict__ member_groups,
    int num_members,
    const int* __restrict__ num_groups_p,
    int* __restrict__ offs)
{
    const int j = blockIdx.x * blockDim.x + threadIdx.x;
    if (j >= num_members) return;
    const int gj = member_groups[j];
    if (j == 0) {
        for (int g = 0; g <= gj; ++g) offs[g] = 0;
    } else {
        const int gp = member_groups[j - 1];
        for (int g = gp + 1; g <= gj; ++g) offs[g] = j;
    }
    if (j == num_members - 1) {
        const int G = *num_groups_p;
        for (int g = gj + 1; g <= G; ++g) offs[g] = num_members;
    }
}

// Pass 2: one wave per batch element; lane = embedding dim.
__global__ __launch_bounds__(256) void consrec_kernel(
    const float* __restrict__ user_emb,
    const float* __restrict__ item_emb,
    const float* __restrict__ w1,     // [64][8]
    const float* __restrict__ b1,     // [8]
    const float* __restrict__ w2,     // [8]
    const float* __restrict__ b2,     // [1]
    const int*   __restrict__ member_users,
    const int*   __restrict__ offs,   // [G+1]
    const int*   __restrict__ group_inputs,
    const int*   __restrict__ item_inputs,
    int batch,
    float* __restrict__ out)
{
    const int wave = (int)((blockIdx.x * blockDim.x + threadIdx.x) >> 6);
    const int lane = threadIdx.x & 63;
    if (wave >= batch) return;

    const int g     = group_inputs[wave];
    const int start = offs[g];
    const int end   = offs[g + 1];
    const int cnt   = end - start;

    // Sum member embeddings; lane d owns dim d. Process members in chunks of
    // 64: one coalesced load of member ids, then readlane-broadcast each id
    // (SGPR base -> coalesced 256B row gather). 4-deep unroll for MLP.
    float sum = 0.f;
    for (int base = start; base < end; base += 64) {
        const int m = min(64, end - base);
        const int uvec = (lane < m) ? member_users[base + lane] : 0;
        int j = 0;
        for (; j + 4 <= m; j += 4) {
            const int u0 = __builtin_amdgcn_readlane(uvec, j + 0);
            const int u1 = __builtin_amdgcn_readlane(uvec, j + 1);
            const int u2 = __builtin_amdgcn_readlane(uvec, j + 2);
            const int u3 = __builtin_amdgcn_readlane(uvec, j + 3);
            const float a0 = user_emb[((size_t)u0 << 6) + lane];
            const float a1 = user_emb[((size_t)u1 << 6) + lane];
            const float a2 = user_emb[((size_t)u2 << 6) + lane];
            const float a3 = user_emb[((size_t)u3 << 6) + lane];
            sum += a0; sum += a1; sum += a2; sum += a3;
        }
        for (; j < m; ++j) {
            const int u = __builtin_amdgcn_readlane(uvec, j);
            sum += user_emb[((size_t)u << 6) + lane];
        }
    }
    const float mean = sum / (float)(cnt > 0 ? cnt : 1);

    const float x = mean * item_emb[(size_t)item_inputs[wave] * EMB + lane];

    // h = relu(x @ w1 + b1): lane d contributes x[d] * w1[d][k]
    float p[8];
    #pragma unroll
    for (int k = 0; k < 8; ++k) p[k] = x * w1[lane * 8 + k];

    #pragma unroll
    for (int off = 32; off >= 1; off >>= 1) {
        #pragma unroll
        for (int k = 0; k < 8; ++k) p[k] += __shfl_xor(p[k], off, 64);
    }

    float acc = b2[0];
    #pragma unroll
    for (int k = 0; k < 8; ++k) {
        float h = p[k] + b1[k];
        h = h > 0.f ? h : 0.f;
        acc += h * w2[k];
    }
    const float y = 1.f / (1.f + expf(-acc));
    if (lane == 0) out[wave] = y;
}

extern "C" void kernel_launch(void* const* d_in, const int* in_sizes, int n_in,
                              void* d_out, int out_size, void* d_ws, size_t ws_size,
                              hipStream_t stream) {
    const float* user_emb      = (const float*)d_in[0];
    const float* item_emb      = (const float*)d_in[1];
    const float* w1            = (const float*)d_in[2];
    const float* b1            = (const float*)d_in[3];
    const float* w2            = (const float*)d_in[4];
    const float* b2            = (const float*)d_in[5];
    const int*   member_users  = (const int*)d_in[6];
    const int*   member_groups = (const int*)d_in[7];
    const int*   group_inputs  = (const int*)d_in[8];
    const int*   item_inputs   = (const int*)d_in[9];
    const int*   num_groups_p  = (const int*)d_in[10];

    const int num_members = in_sizes[6];
    const int batch       = in_sizes[8];

    int* offs = (int*)d_ws;   // (G+1) ints, G = 100000 -> ~400 KB, fits ws

    {
        const int threads = 256;
        const int grid = (num_members + threads - 1) / threads;
        boundaries_kernel<<<grid, threads, 0, stream>>>(
            member_groups, num_members, num_groups_p, offs);
    }
    {
        const int threads = 256;                 // 4 waves/block
        const int waves_per_block = threads / 64;
        const int grid = (batch + waves_per_block - 1) / waves_per_block;
        consrec_kernel<<<grid, threads, 0, stream>>>(
            user_emb, item_emb, w1, b1, w2, b2,
            member_users, offs, group_inputs, item_inputs,
            batch, (float*)d_out);
    }
}